// Round 18
// baseline (227.887 us; speedup 1.0000x reference)
//
#include <hip/hip_runtime.h>
#include <stdint.h>

// =====================================================================
// Host-side RNG (HW-VERIFIED r7) — DO NOT TOUCH.
// =====================================================================
namespace rng42 {
typedef unsigned __int128 u128;

static inline uint32_t hashmix(uint32_t v, uint32_t& hc) {
    v ^= hc;
    hc *= 0x931e8875u;
    v *= hc;
    v ^= v >> 16;
    return v;
}
static inline uint32_t mixf(uint32_t x, uint32_t y) {
    uint32_t r = x * 0xca01f9ddu - y * 0x4973f715u;
    r ^= r >> 16;
    return r;
}

struct PCG64 {
    u128 state, inc;
    bool has32; uint32_t buf32;
    static inline u128 mult() {
        return ((u128)2549297995355413924ULL << 64) | (u128)4865540595714422341ULL;
    }
    inline void step() { state = state * mult() + inc; }
    void seed42() {
        uint32_t pool[4];
        uint32_t hc = 0x43b0d7e5u;
        pool[0] = hashmix(42u, hc);
        for (int i = 1; i < 4; i++) pool[i] = hashmix(0u, hc);
        for (int s = 0; s < 4; s++)
            for (int d = 0; d < 4; d++)
                if (s != d) pool[d] = mixf(pool[d], hashmix(pool[s], hc));
        uint32_t hb = 0x8b51f9ddu;
        uint32_t st32[8];
        for (int i = 0; i < 8; i++) {
            uint32_t dv = pool[i & 3];
            dv ^= hb;
            hb *= 0x58f38dedu;
            dv *= hb;
            dv ^= dv >> 16;
            st32[i] = dv;
        }
        uint64_t w0 = (uint64_t)st32[0] | ((uint64_t)st32[1] << 32);
        uint64_t w1 = (uint64_t)st32[2] | ((uint64_t)st32[3] << 32);
        uint64_t w2 = (uint64_t)st32[4] | ((uint64_t)st32[5] << 32);
        uint64_t w3 = (uint64_t)st32[6] | ((uint64_t)st32[7] << 32);
        u128 initstate = ((u128)w0 << 64) | (u128)w1;
        u128 initseq   = ((u128)w2 << 64) | (u128)w3;
        state = 0;
        inc = (initseq << 1) | 1;
        step();
        state += initstate;
        step();
        has32 = false; buf32 = 0;
    }
    uint64_t next64() {
        step();
        uint64_t lo = (uint64_t)state, hi = (uint64_t)(state >> 64);
        uint64_t x = hi ^ lo;
        unsigned rot = (unsigned)(uint64_t)(state >> 122);
        return (x >> rot) | (x << ((64u - rot) & 63u));
    }
    uint32_t next32() {
        if (has32) { has32 = false; return buf32; }
        uint64_t n = next64();
        has32 = true;
        buf32 = (uint32_t)(n >> 32);
        return (uint32_t)(n & 0xffffffffu);
    }
    uint32_t lemire32(uint32_t rng) {
        const uint32_t rng_excl = rng + 1u;
        uint64_t m = (uint64_t)next32() * (uint64_t)rng_excl;
        uint32_t leftover = (uint32_t)m;
        if (leftover < rng_excl) {
            const uint32_t threshold = (uint32_t)(0xFFFFFFFFu - rng) % rng_excl;
            while (leftover < threshold) {
                m = (uint64_t)next32() * (uint64_t)rng_excl;
                leftover = (uint32_t)m;
            }
        }
        return (uint32_t)(m >> 32);
    }
    uint32_t interval(uint32_t mx) {
        if (mx == 0) return 0;
        uint32_t mask = mx;
        mask |= mask >> 1; mask |= mask >> 2; mask |= mask >> 4;
        mask |= mask >> 8; mask |= mask >> 16;
        uint32_t value;
        while ((value = (next32() & mask)) > mx) {}
        return value;
    }
};
} // namespace rng42

struct OpsArg { int v[50]; };

static void gen_ops(OpsArg& o) {
    rng42::PCG64 g;
    g.seed42();
    for (int k = 0; k < 50; k++) {
        int t = (int)g.lemire32(3);
        if (t == 3) {
            int arr[4] = {0, 1, 2, 3};
            for (int i = 3; i >= 1; i--) {
                int j = (int)g.interval((uint32_t)i);
                if (i != j) { int tmp = arr[i]; arr[i] = arr[j]; arr[j] = tmp; }
            }
            o.v[k] = 3 | (arr[0] << 2) | (arr[1] << 4);
        } else {
            int w = (int)g.lemire32(3);
            o.v[k] = t | (w << 2);
        }
    }
}

static int anchors_mask() {
    rng42::PCG64 g;
    g.seed42();
    uint32_t c[6];
    for (int i = 0; i < 6; i++) c[i] = g.next32();
    int m = 0;
    if (c[1] >= 3324113900u && c[1] <= 3324117900u) m |= 1;
    if (c[3] >= 1884966500u && c[3] <= 1884970500u) m |= 2;
    if (c[5] >= 3687648000u && c[5] <= 3687652000u) m |= 4;
    return m;
}

static float diag_payload(int mask) {
    rng42::PCG64 g;
    g.seed42();
    uint64_t D = 0;
    for (int k = 0; k < 5; k++) {
        uint32_t c = g.next32();
        D = D * 10ull + (uint32_t)(((uint64_t)c * 10ull) >> 32);
    }
    return (float)((double)(2 + mask) * 1e7 + (double)D * 10.0);
}

// =====================================================================
// Quantum gate primitives (verified r7). State idx = q0*8+q1*4+q2*2+q3.
// =====================================================================
template<int MASK>
__device__ inline void g_rx(float c, float s, float* re, float* im) {
#pragma unroll
    for (int i = 0; i < 16; i++)
        if (!(i & MASK)) {
            const int j = i | MASK;
            float r0 = re[i], i0 = im[i], r1 = re[j], i1 = im[j];
            re[i] = c * r0 + s * i1; im[i] = c * i0 - s * r1;
            re[j] = s * i0 + c * r1; im[j] = c * i1 - s * r0;
        }
}
template<int MASK>
__device__ inline void g_ry(float c, float s, float* re, float* im) {
#pragma unroll
    for (int i = 0; i < 16; i++)
        if (!(i & MASK)) {
            const int j = i | MASK;
            float r0 = re[i], i0 = im[i], r1 = re[j], i1 = im[j];
            re[i] = c * r0 - s * r1; im[i] = c * i0 - s * i1;
            re[j] = s * r0 + c * r1; im[j] = s * i0 + c * i1;
        }
}
template<int MASK>
__device__ inline void g_rz(float c, float s, float* re, float* im) {
#pragma unroll
    for (int i = 0; i < 16; i++)
        if (!(i & MASK)) {
            const int j = i | MASK;
            float r0 = re[i], i0 = im[i], r1 = re[j], i1 = im[j];
            re[i] = c * r0 + s * i0; im[i] = c * i0 - s * r0;
            re[j] = c * r1 - s * i1; im[j] = c * i1 + s * r1;
        }
}
template<int CM, int TM>
__device__ inline void g_cnot(float* re, float* im) {
#pragma unroll
    for (int i = 0; i < 16; i++)
        if ((i & CM) && !(i & TM)) {
            const int j = i | TM;
            float tr = re[i]; re[i] = re[j]; re[j] = tr;
            float ti = im[i]; im[i] = im[j]; im[j] = ti;
        }
}

__device__ inline void rot_rt(int ty, int w, float c, float s, float* re, float* im) {
    switch (ty * 4 + w) {
        case 0:  g_rx<8>(c, s, re, im); break;
        case 1:  g_rx<4>(c, s, re, im); break;
        case 2:  g_rx<2>(c, s, re, im); break;
        case 3:  g_rx<1>(c, s, re, im); break;
        case 4:  g_ry<8>(c, s, re, im); break;
        case 5:  g_ry<4>(c, s, re, im); break;
        case 6:  g_ry<2>(c, s, re, im); break;
        case 7:  g_ry<1>(c, s, re, im); break;
        case 8:  g_rz<8>(c, s, re, im); break;
        case 9:  g_rz<4>(c, s, re, im); break;
        case 10: g_rz<2>(c, s, re, im); break;
        case 11: g_rz<1>(c, s, re, im); break;
        default: break;
    }
}
__device__ inline void cnot_rt(int w0, int w1, float* re, float* im) {
    switch (w0 * 4 + w1) {
        case 1:  g_cnot<8, 4>(re, im); break;
        case 2:  g_cnot<8, 2>(re, im); break;
        case 3:  g_cnot<8, 1>(re, im); break;
        case 4:  g_cnot<4, 8>(re, im); break;
        case 6:  g_cnot<4, 2>(re, im); break;
        case 7:  g_cnot<4, 1>(re, im); break;
        case 8:  g_cnot<2, 8>(re, im); break;
        case 9:  g_cnot<2, 4>(re, im); break;
        case 11: g_cnot<2, 1>(re, im); break;
        case 12: g_cnot<1, 8>(re, im); break;
        case 13: g_cnot<1, 4>(re, im); break;
        case 14: g_cnot<1, 2>(re, im); break;
        default: break;
    }
}

// swizzled channel-last site index for c1 (14x14): row pad + col skew
__device__ inline int c1site(int y, int x) { return y * 15 + x + (x >> 2); }

__device__ inline float dot4(const float4& w, const float4& p) {
    return w.x * p.x + w.y * p.y + w.z * p.z + w.w * p.w;
}

// =====================================================================
// K1: per-image CNN — r17 body, TWO images per block (grid 2048):
// weight staging (cw1/cb1/wl2-permute/cb2) hoisted out of the image
// loop; per-image phases unchanged. No new per-thread state.
// Do NOT add a min-waves arg to __launch_bounds__ (spill trap, r8/r10).
// Do NOT grow per-thread state in conv2 (occupancy trap, r13).
// =====================================================================
__global__ __launch_bounds__(256) void k_cnn(
    const float* __restrict__ x,
    const float* __restrict__ c1w, const float* __restrict__ c1b,
    const float* __restrict__ c2w, const float* __restrict__ c2b,
    const float* __restrict__ w1, const float* __restrict__ b1,
    const float* __restrict__ w2, const float* __restrict__ b2,
    const float* __restrict__ w3, const float* __restrict__ b3,
    float* __restrict__ pooled_g, float* __restrict__ mlp_g)
{
    __shared__ __align__(16) float xs[784];
    __shared__ __align__(16) float c1s[216 * 8];
    __shared__ __align__(16) float c2s[784];
    __shared__ __align__(16) float cw1[72], cb1[8], wl2[1152], cb2[16];
    __shared__ float h1s[8];

    const int t = threadIdx.x;

    // ---- staging shared by both images ----
    if (t < 72) cw1[t] = c1w[t];
    if (t < 8) cb1[t] = c1b[t];
    if (t < 144) {  // cheap permute: t = oc*9+k9, unrolled over 8 ic
        const int oc = t / 9, k9 = t - oc * 9;
        const float* src = c2w + oc * 72 + k9;
        float* dst = wl2 + t * 8;
#pragma unroll
        for (int ic = 0; ic < 8; ic++) dst[ic] = src[ic * 9];
    }
    if (t < 16) cb2[t] = c2b[t];

#pragma unroll 1
    for (int img = 0; img < 2; img++) {
        const int b = blockIdx.x * 2 + img;
        __syncthreads();   // staging done (img 0) / prev image done (img 1)

        const float4* xb4 = (const float4*)(x + b * 784);
        if (t < 196) ((float4*)xs)[t] = xb4[t];
        __syncthreads();

        // avg-pool 6x6 stride 6 -> pooled[16]
        if (t < 16) {
            int r0 = (t >> 2) * 6, c0 = (t & 3) * 6;
            float s = 0.f;
#pragma unroll
            for (int dy = 0; dy < 6; dy++)
#pragma unroll
                for (int dx = 0; dx < 6; dx++)
                    s += xs[(r0 + dy) * 28 + (c0 + dx)];
            pooled_g[b * 16 + t] = s * (1.0f / 36.0f);
        }

        // conv1 + relu + 2x2 maxpool: 196 threads x 8 oc
        if (t < 196) {
            const int py = t / 14, px = t % 14;
            const int y0 = 2 * py - 1, x0 = 2 * px - 1;
            float patch[16];
#pragma unroll
            for (int i = 0; i < 4; i++)
#pragma unroll
                for (int j = 0; j < 4; j++) {
                    int yy = y0 + i, xx = x0 + j;
                    patch[i * 4 + j] = (yy >= 0 && yy < 28 && xx >= 0 && xx < 28)
                                           ? xs[yy * 28 + xx] : 0.f;
                }
            float m8[8];
#pragma unroll
            for (int oc = 0; oc < 8; oc++) {
                float w[9];
#pragma unroll
                for (int i = 0; i < 9; i++) w[i] = cw1[oc * 9 + i];
                float m = 0.f;
#pragma unroll
                for (int dy = 0; dy < 2; dy++)
#pragma unroll
                    for (int dx = 0; dx < 2; dx++) {
                        float acc = cb1[oc];
#pragma unroll
                        for (int ky = 0; ky < 3; ky++)
#pragma unroll
                            for (int kx = 0; kx < 3; kx++)
                                acc += w[ky * 3 + kx] * patch[(dy + ky) * 4 + (dx + kx)];
                        m = fmaxf(m, acc);
                    }
                m8[oc] = m;
            }
            float4* cv = (float4*)&c1s[c1site(py, px) * 8];
            cv[0] = make_float4(m8[0], m8[1], m8[2], m8[3]);
            cv[1] = make_float4(m8[4], m8[5], m8[6], m8[7]);
        }
        __syncthreads();

        // conv2 + relu + 2x2 maxpool: thread = (oc = t&15, pbase = t>>4)
        {
            const int oc = t & 15;
            const int pbase = t >> 4;
            const float bias = cb2[oc];
            float a[4][2][2];
#pragma unroll
            for (int pi = 0; pi < 4; pi++)
#pragma unroll
                for (int dy = 0; dy < 2; dy++)
#pragma unroll
                    for (int dx = 0; dx < 2; dx++) a[pi][dy][dx] = bias;

            const float4* wv = (const float4*)wl2;
            const float4* cv = (const float4*)c1s;
            const float4 z4 = make_float4(0.f, 0.f, 0.f, 0.f);

#pragma unroll
            for (int h = 0; h < 2; h++) {
                float4 W[9];
#pragma unroll
                for (int k = 0; k < 9; k++) W[k] = wv[(oc * 9 + k) * 2 + h];
#pragma unroll
                for (int pi = 0; pi < 4; pi++) {
                    const int p = pbase + 16 * pi;
                    if (p < 49) {
                        const int py = p / 7, px = p % 7;
                        const int y0 = 2 * py - 1, x0 = 2 * px - 1;
#pragma unroll
                        for (int i = 0; i < 4; i++) {
                            const int y = y0 + i;
                            float4 r[4];
                            if (y >= 0 && y < 14) {
#pragma unroll
                                for (int j = 0; j < 4; j++) {
                                    const int xc = x0 + j;
                                    r[j] = (xc >= 0 && xc < 14)
                                               ? cv[c1site(y, xc) * 2 + h] : z4;
                                }
                            } else {
#pragma unroll
                                for (int j = 0; j < 4; j++) r[j] = z4;
                            }
#pragma unroll
                            for (int dy = 0; dy < 2; dy++) {
                                if (dy <= i && i <= dy + 2) {
                                    const int ky = i - dy;
                                    const float4 wk0 = W[ky * 3 + 0];
                                    const float4 wk1 = W[ky * 3 + 1];
                                    const float4 wk2 = W[ky * 3 + 2];
                                    a[pi][dy][0] += dot4(wk0, r[0]) + dot4(wk1, r[1]) + dot4(wk2, r[2]);
                                    a[pi][dy][1] += dot4(wk0, r[1]) + dot4(wk1, r[2]) + dot4(wk2, r[3]);
                                }
                            }
                        }
                    }
                }
            }
#pragma unroll
            for (int pi = 0; pi < 4; pi++) {
                const int p = pbase + 16 * pi;
                if (p < 49) {
                    float m = fmaxf(fmaxf(a[pi][0][0], a[pi][0][1]),
                                    fmaxf(a[pi][1][0], a[pi][1][1]));
                    c2s[oc * 49 + p] = fmaxf(m, 0.f);
                }
            }
        }
        __syncthreads();

        // MLP layer1: 8 outputs x 32 lanes each
        {
            int o = t >> 5, lane = t & 31;
            float s = 0.f;
            const float* wrow = w1 + o * 784;
            for (int k = lane; k < 784; k += 32) s += c2s[k] * wrow[k];
#pragma unroll
            for (int d = 16; d > 0; d >>= 1) s += __shfl_down(s, d, 32);
            if (lane == 0) h1s[o] = tanhf(s + b1[o]);
        }
        __syncthreads();
        if (t == 0) {
            float h2[4];
#pragma unroll
            for (int o = 0; o < 4; o++) {
                float s = b2[o];
#pragma unroll
                for (int j = 0; j < 8; j++) s += h1s[j] * w2[o * 8 + j];
                h2[o] = tanhf(s);
            }
            float s = b3[0];
#pragma unroll
            for (int j = 0; j < 4; j++) s += h2[j] * w3[j];
            mlp_g[b] = s;
        }
    }
}

// =====================================================================
// K2: quantum block (unchanged, verified). Block = 1 wave; emits part1.
// =====================================================================
__global__ __launch_bounds__(64) void k_quantum(
    const float* __restrict__ pooled_g, const float* __restrict__ rl,
    const float* __restrict__ prx0, const float* __restrict__ pry0,
    const float* __restrict__ prz0, const float* __restrict__ pcrx0,
    float* __restrict__ qout, float* __restrict__ part1, OpsArg ops)
{
    __shared__ float rc[50], rs[50];
    const int t = threadIdx.x;
    if (t < 50) {
        float a = 0.5f * rl[t];
        rc[t] = cosf(a);
        rs[t] = sinf(a);
    }
    __syncthreads();

    const int b = blockIdx.x * 64 + t;
    float re[16], im[16];
#pragma unroll
    for (int i = 0; i < 16; i++) { re[i] = 0.f; im[i] = 0.f; }
    re[0] = 1.f;

    const float4* pv = (const float4*)(pooled_g + b * 16);
    float pb[16];
    {
        float4 p0 = pv[0], p1 = pv[1], p2 = pv[2], p3 = pv[3];
        pb[0] = p0.x; pb[1] = p0.y; pb[2] = p0.z; pb[3] = p0.w;
        pb[4] = p1.x; pb[5] = p1.y; pb[6] = p1.z; pb[7] = p1.w;
        pb[8] = p2.x; pb[9] = p2.y; pb[10] = p2.z; pb[11] = p2.w;
        pb[12] = p3.x; pb[13] = p3.y; pb[14] = p3.z; pb[15] = p3.w;
    }
    {
        float c, s, a;
        a = 0.5f * pb[0];  c = cosf(a); s = sinf(a); g_ry<8>(c, s, re, im);
        a = 0.5f * pb[1];  c = cosf(a); s = sinf(a); g_ry<4>(c, s, re, im);
        a = 0.5f * pb[2];  c = cosf(a); s = sinf(a); g_ry<2>(c, s, re, im);
        a = 0.5f * pb[3];  c = cosf(a); s = sinf(a); g_ry<1>(c, s, re, im);
        a = 0.5f * pb[4];  c = cosf(a); s = sinf(a); g_rz<8>(c, s, re, im);
        a = 0.5f * pb[5];  c = cosf(a); s = sinf(a); g_rz<4>(c, s, re, im);
        a = 0.5f * pb[6];  c = cosf(a); s = sinf(a); g_rz<2>(c, s, re, im);
        a = 0.5f * pb[7];  c = cosf(a); s = sinf(a); g_rz<1>(c, s, re, im);
        a = 0.5f * pb[8];  c = cosf(a); s = sinf(a); g_rx<8>(c, s, re, im);
        a = 0.5f * pb[9];  c = cosf(a); s = sinf(a); g_rx<4>(c, s, re, im);
        a = 0.5f * pb[10]; c = cosf(a); s = sinf(a); g_rx<2>(c, s, re, im);
        a = 0.5f * pb[11]; c = cosf(a); s = sinf(a); g_rx<1>(c, s, re, im);
        a = 0.5f * pb[12]; c = cosf(a); s = sinf(a); g_ry<8>(c, s, re, im);
        a = 0.5f * pb[13]; c = cosf(a); s = sinf(a); g_ry<4>(c, s, re, im);
        a = 0.5f * pb[14]; c = cosf(a); s = sinf(a); g_ry<2>(c, s, re, im);
        a = 0.5f * pb[15]; c = cosf(a); s = sinf(a); g_ry<1>(c, s, re, im);
    }

#pragma unroll 1
    for (int k = 0; k < 50; k++) {
        int v = ops.v[k];
        int ty = v & 3;
        int w0 = (v >> 2) & 3;
        int w1 = (v >> 4) & 3;
        if (ty == 3) cnot_rt(w0, w1, re, im);
        else         rot_rt(ty, w0, rc[k], rs[k], re, im);
    }

    { float a = 0.5f * prx0[0];  g_rx<8>(cosf(a), sinf(a), re, im); }
    { float a = 0.5f * pry0[0];  g_ry<4>(cosf(a), sinf(a), re, im); }
    { float a = 0.5f * prz0[0];  g_rz<1>(cosf(a), sinf(a), re, im); }
    { // crx (control wire0=mask8, target wire2=mask2)
        float a = 0.5f * pcrx0[0];
        float c = cosf(a), s = sinf(a);
#pragma unroll
        for (int i = 0; i < 16; i++)
            if ((i & 8) && !(i & 2)) {
                const int j = i | 2;
                float r0 = re[i], i0 = im[i], r1 = re[j], i1 = im[j];
                re[i] = c * r0 + s * i1; im[i] = c * i0 - s * r1;
                re[j] = s * i0 + c * r1; im[j] = c * i1 - s * r0;
            }
    }
    { // H wire 3
        const float r2 = 0.70710678118654752f;
#pragma unroll
        for (int i = 0; i < 16; i++)
            if (!(i & 1)) {
                const int j = i | 1;
                float r0 = re[i], i0 = im[i], r1 = re[j], i1 = im[j];
                re[i] = (r0 + r1) * r2; im[i] = (i0 + i1) * r2;
                re[j] = (r0 - r1) * r2; im[j] = (i0 - i1) * r2;
            }
    }
    { // SX wire 2
#pragma unroll
        for (int i = 0; i < 16; i++)
            if (!(i & 2)) {
                const int j = i | 2;
                float r0 = re[i], i0 = im[i], r1 = re[j], i1 = im[j];
                re[i] = 0.5f * (r0 - i0 + r1 + i1);
                im[i] = 0.5f * (r0 + i0 - r1 + i1);
                re[j] = 0.5f * (r0 + i0 + r1 - i1);
                im[j] = 0.5f * (i0 - r0 + r1 + i1);
            }
    }
    g_cnot<1, 8>(re, im);

    float e0 = 0.f, e1 = 0.f, e2 = 0.f, e3 = 0.f;
#pragma unroll
    for (int i = 0; i < 16; i++) {
        float p = re[i] * re[i] + im[i] * im[i];
        e0 += (i & 8) ? -p : p;
        e1 += (i & 4) ? -p : p;
        e2 += (i & 2) ? -p : p;
        e3 += (i & 1) ? -p : p;
    }
    qout[b * 4 + 0] = e0;
    qout[b * 4 + 1] = e1;
    qout[b * 4 + 2] = e2;
    qout[b * 4 + 3] = e3;

    float v0 = e0, v1 = e1, v2 = e2, v3 = e3;
    float q0 = e0 * e0, q1 = e1 * e1, q2 = e2 * e2, q3 = e3 * e3;
#pragma unroll
    for (int d = 32; d > 0; d >>= 1) {
        v0 += __shfl_down(v0, d); v1 += __shfl_down(v1, d);
        v2 += __shfl_down(v2, d); v3 += __shfl_down(v3, d);
        q0 += __shfl_down(q0, d); q1 += __shfl_down(q1, d);
        q2 += __shfl_down(q2, d); q3 += __shfl_down(q3, d);
    }
    if (t == 0) {
        float* p1 = part1 + blockIdx.x * 8;
        p1[0] = v0; p1[1] = v1; p1[2] = v2; p1[3] = v3;
        p1[4] = q0; p1[5] = q1; p1[6] = q2; p1[7] = q3;
    }
}

// =====================================================================
// K3 (fused epilogue): ONE block, 1024 threads (16 waves).
// =====================================================================
__global__ __launch_bounds__(1024) void k_epilogue(
    const float* __restrict__ qout, const float* __restrict__ mlp,
    const float* __restrict__ part1,
    const float* __restrict__ qg, const float* __restrict__ qb,
    const float* __restrict__ fw, const float* __restrict__ fb,
    const float* __restrict__ fg, const float* __restrict__ fbb,
    float* __restrict__ out)
{
    __shared__ float st1[8];
    __shared__ float st2[8];
    __shared__ float wred[16][8];
    __shared__ __align__(16) float fbuf[16384];

    const int t = threadIdx.x;
    const int wave = t >> 6, lane = t & 63;

    if (t < 64) {
        float s[8];
#pragma unroll
        for (int j = 0; j < 8; j++) s[j] = part1[t * 8 + j];
#pragma unroll
        for (int d = 32; d > 0; d >>= 1)
#pragma unroll
            for (int j = 0; j < 8; j++) s[j] += __shfl_down(s[j], d);
        if (t == 0) {
#pragma unroll
            for (int j = 0; j < 4; j++) {
                float mean = s[j] * (1.0f / 4096.0f);
                float var = fmaxf(s[4 + j] * (1.0f / 4096.0f) - mean * mean, 0.0f);
                st1[j] = mean;
                st1[4 + j] = 1.0f / sqrtf(var + 1e-5f);
            }
        }
    }
    __syncthreads();

    float ps[8];
#pragma unroll
    for (int j = 0; j < 8; j++) ps[j] = 0.f;
#pragma unroll
    for (int r = 0; r < 4; r++) {
        const int row = r * 1024 + t;
        const float4 q = ((const float4*)qout)[row];
        float c[5];
        c[0] = mlp[row];
        c[1] = (q.x - st1[0]) * st1[4] * qg[0] + qb[0];
        c[2] = (q.y - st1[1]) * st1[5] * qg[1] + qb[1];
        c[3] = (q.z - st1[2]) * st1[6] * qg[2] + qb[2];
        c[4] = (q.w - st1[3]) * st1[7] * qg[3] + qb[3];
        float fv[4];
#pragma unroll
        for (int o = 0; o < 4; o++) {
            float s = fb[o];
#pragma unroll
            for (int j = 0; j < 5; j++) s += fw[o * 5 + j] * c[j];
            fv[o] = s;
        }
        ((float4*)fbuf)[row] = make_float4(fv[0], fv[1], fv[2], fv[3]);
#pragma unroll
        for (int j = 0; j < 4; j++) {
            ps[j] += fv[j];
            ps[4 + j] += fv[j] * fv[j];
        }
    }
#pragma unroll
    for (int d = 32; d > 0; d >>= 1)
#pragma unroll
        for (int j = 0; j < 8; j++) ps[j] += __shfl_down(ps[j], d);
    if (lane == 0) {
#pragma unroll
        for (int j = 0; j < 8; j++) wred[wave][j] = ps[j];
    }
    __syncthreads();
    if (t < 8) {
        float s = 0.f;
#pragma unroll
        for (int w = 0; w < 16; w++) s += wred[w][t];
        wred[0][t] = s;
    }
    __syncthreads();
    if (t < 4) {
        float mean = wred[0][t] * (1.0f / 4096.0f);
        float var = fmaxf(wred[0][4 + t] * (1.0f / 4096.0f) - mean * mean, 0.0f);
        st2[t] = mean;
        st2[4 + t] = 1.0f / sqrtf(var + 1e-5f);
    }
    __syncthreads();

#pragma unroll
    for (int r = 0; r < 4; r++) {
        const int row = r * 1024 + t;
        const float4 v = ((const float4*)fbuf)[row];
        float4 o;
        o.x = (v.x - st2[0]) * st2[4] * fg[0] + fbb[0];
        o.y = (v.y - st2[1]) * st2[5] * fg[1] + fbb[1];
        o.z = (v.z - st2[2]) * st2[6] * fg[2] + fbb[2];
        o.w = (v.w - st2[3]) * st2[7] * fg[3] + fbb[3];
        ((float4*)out)[row] = o;
    }
}

// K4: diagnostic — only launched if anchors fail
__global__ void k_diag(float* __restrict__ out, float payload)
{
    out[0] = payload;
}

// =====================================================================
extern "C" void kernel_launch(void* const* d_in, const int* in_sizes, int n_in,
                              void* d_out, int out_size, void* d_ws, size_t ws_size,
                              hipStream_t stream) {
    (void)in_sizes; (void)n_in; (void)out_size; (void)ws_size;
    const float* x    = (const float*)d_in[0];
    const float* c1w  = (const float*)d_in[1];
    const float* c1b  = (const float*)d_in[2];
    const float* c2w  = (const float*)d_in[3];
    const float* c2b  = (const float*)d_in[4];
    const float* w1   = (const float*)d_in[5];
    const float* b1   = (const float*)d_in[6];
    const float* w2   = (const float*)d_in[7];
    const float* b2   = (const float*)d_in[8];
    const float* w3   = (const float*)d_in[9];
    const float* b3   = (const float*)d_in[10];
    const float* rl   = (const float*)d_in[11];
    const float* rx0  = (const float*)d_in[12];
    const float* ry0  = (const float*)d_in[13];
    const float* rz0  = (const float*)d_in[14];
    const float* crx0 = (const float*)d_in[15];
    const float* bqg  = (const float*)d_in[16];
    const float* bqb  = (const float*)d_in[17];
    const float* fw   = (const float*)d_in[18];
    const float* fb   = (const float*)d_in[19];
    const float* bfg  = (const float*)d_in[20];
    const float* bfb  = (const float*)d_in[21];

    float* ws = (float*)d_ws;
    float* pooled = ws;            // 4096*16
    float* mlp    = ws + 65536;    // 4096
    float* qout   = ws + 69632;    // 4096*4
    float* part1  = ws + 102400;   // 64*8

    OpsArg ops;
    gen_ops(ops);
    int am = anchors_mask();

    k_cnn<<<2048, 256, 0, stream>>>(x, c1w, c1b, c2w, c2b, w1, b1, w2, b2, w3, b3,
                                    pooled, mlp);
    k_quantum<<<64, 64, 0, stream>>>(pooled, rl, rx0, ry0, rz0, crx0, qout, part1, ops);
    k_epilogue<<<1, 1024, 0, stream>>>(qout, mlp, part1, bqg, bqb, fw, fb,
                                       bfg, bfb, (float*)d_out);
    if (am != 7) {
        k_diag<<<1, 1, 0, stream>>>((float*)d_out, diag_payload(am));
    }
}

// Round 19
// 141.200 us; speedup vs baseline: 1.6139x; 1.6139x over previous
//
#include <hip/hip_runtime.h>
#include <stdint.h>

// =====================================================================
// Host-side RNG (HW-VERIFIED r7) — DO NOT TOUCH.
// =====================================================================
namespace rng42 {
typedef unsigned __int128 u128;

static inline uint32_t hashmix(uint32_t v, uint32_t& hc) {
    v ^= hc;
    hc *= 0x931e8875u;
    v *= hc;
    v ^= v >> 16;
    return v;
}
static inline uint32_t mixf(uint32_t x, uint32_t y) {
    uint32_t r = x * 0xca01f9ddu - y * 0x4973f715u;
    r ^= r >> 16;
    return r;
}

struct PCG64 {
    u128 state, inc;
    bool has32; uint32_t buf32;
    static inline u128 mult() {
        return ((u128)2549297995355413924ULL << 64) | (u128)4865540595714422341ULL;
    }
    inline void step() { state = state * mult() + inc; }
    void seed42() {
        uint32_t pool[4];
        uint32_t hc = 0x43b0d7e5u;
        pool[0] = hashmix(42u, hc);
        for (int i = 1; i < 4; i++) pool[i] = hashmix(0u, hc);
        for (int s = 0; s < 4; s++)
            for (int d = 0; d < 4; d++)
                if (s != d) pool[d] = mixf(pool[d], hashmix(pool[s], hc));
        uint32_t hb = 0x8b51f9ddu;
        uint32_t st32[8];
        for (int i = 0; i < 8; i++) {
            uint32_t dv = pool[i & 3];
            dv ^= hb;
            hb *= 0x58f38dedu;
            dv *= hb;
            dv ^= dv >> 16;
            st32[i] = dv;
        }
        uint64_t w0 = (uint64_t)st32[0] | ((uint64_t)st32[1] << 32);
        uint64_t w1 = (uint64_t)st32[2] | ((uint64_t)st32[3] << 32);
        uint64_t w2 = (uint64_t)st32[4] | ((uint64_t)st32[5] << 32);
        uint64_t w3 = (uint64_t)st32[6] | ((uint64_t)st32[7] << 32);
        u128 initstate = ((u128)w0 << 64) | (u128)w1;
        u128 initseq   = ((u128)w2 << 64) | (u128)w3;
        state = 0;
        inc = (initseq << 1) | 1;
        step();
        state += initstate;
        step();
        has32 = false; buf32 = 0;
    }
    uint64_t next64() {
        step();
        uint64_t lo = (uint64_t)state, hi = (uint64_t)(state >> 64);
        uint64_t x = hi ^ lo;
        unsigned rot = (unsigned)(uint64_t)(state >> 122);
        return (x >> rot) | (x << ((64u - rot) & 63u));
    }
    uint32_t next32() {
        if (has32) { has32 = false; return buf32; }
        uint64_t n = next64();
        has32 = true;
        buf32 = (uint32_t)(n >> 32);
        return (uint32_t)(n & 0xffffffffu);
    }
    uint32_t lemire32(uint32_t rng) {
        const uint32_t rng_excl = rng + 1u;
        uint64_t m = (uint64_t)next32() * (uint64_t)rng_excl;
        uint32_t leftover = (uint32_t)m;
        if (leftover < rng_excl) {
            const uint32_t threshold = (uint32_t)(0xFFFFFFFFu - rng) % rng_excl;
            while (leftover < threshold) {
                m = (uint64_t)next32() * (uint64_t)rng_excl;
                leftover = (uint32_t)m;
            }
        }
        return (uint32_t)(m >> 32);
    }
    uint32_t interval(uint32_t mx) {
        if (mx == 0) return 0;
        uint32_t mask = mx;
        mask |= mask >> 1; mask |= mask >> 2; mask |= mask >> 4;
        mask |= mask >> 8; mask |= mask >> 16;
        uint32_t value;
        while ((value = (next32() & mask)) > mx) {}
        return value;
    }
};
} // namespace rng42

struct OpsArg { int v[50]; };

static void gen_ops(OpsArg& o) {
    rng42::PCG64 g;
    g.seed42();
    for (int k = 0; k < 50; k++) {
        int t = (int)g.lemire32(3);
        if (t == 3) {
            int arr[4] = {0, 1, 2, 3};
            for (int i = 3; i >= 1; i--) {
                int j = (int)g.interval((uint32_t)i);
                if (i != j) { int tmp = arr[i]; arr[i] = arr[j]; arr[j] = tmp; }
            }
            o.v[k] = 3 | (arr[0] << 2) | (arr[1] << 4);
        } else {
            int w = (int)g.lemire32(3);
            o.v[k] = t | (w << 2);
        }
    }
}

static int anchors_mask() {
    rng42::PCG64 g;
    g.seed42();
    uint32_t c[6];
    for (int i = 0; i < 6; i++) c[i] = g.next32();
    int m = 0;
    if (c[1] >= 3324113900u && c[1] <= 3324117900u) m |= 1;
    if (c[3] >= 1884966500u && c[3] <= 1884970500u) m |= 2;
    if (c[5] >= 3687648000u && c[5] <= 3687652000u) m |= 4;
    return m;
}

static float diag_payload(int mask) {
    rng42::PCG64 g;
    g.seed42();
    uint64_t D = 0;
    for (int k = 0; k < 5; k++) {
        uint32_t c = g.next32();
        D = D * 10ull + (uint32_t)(((uint64_t)c * 10ull) >> 32);
    }
    return (float)((double)(2 + mask) * 1e7 + (double)D * 10.0);
}

// =====================================================================
// Quantum gate primitives (verified r7). State idx = q0*8+q1*4+q2*2+q3.
// =====================================================================
template<int MASK>
__device__ inline void g_rx(float c, float s, float* re, float* im) {
#pragma unroll
    for (int i = 0; i < 16; i++)
        if (!(i & MASK)) {
            const int j = i | MASK;
            float r0 = re[i], i0 = im[i], r1 = re[j], i1 = im[j];
            re[i] = c * r0 + s * i1; im[i] = c * i0 - s * r1;
            re[j] = s * i0 + c * r1; im[j] = c * i1 - s * r0;
        }
}
template<int MASK>
__device__ inline void g_ry(float c, float s, float* re, float* im) {
#pragma unroll
    for (int i = 0; i < 16; i++)
        if (!(i & MASK)) {
            const int j = i | MASK;
            float r0 = re[i], i0 = im[i], r1 = re[j], i1 = im[j];
            re[i] = c * r0 - s * r1; im[i] = c * i0 - s * i1;
            re[j] = s * r0 + c * r1; im[j] = s * i0 + c * i1;
        }
}
template<int MASK>
__device__ inline void g_rz(float c, float s, float* re, float* im) {
#pragma unroll
    for (int i = 0; i < 16; i++)
        if (!(i & MASK)) {
            const int j = i | MASK;
            float r0 = re[i], i0 = im[i], r1 = re[j], i1 = im[j];
            re[i] = c * r0 + s * i0; im[i] = c * i0 - s * r0;
            re[j] = c * r1 - s * i1; im[j] = c * i1 + s * r1;
        }
}
template<int CM, int TM>
__device__ inline void g_cnot(float* re, float* im) {
#pragma unroll
    for (int i = 0; i < 16; i++)
        if ((i & CM) && !(i & TM)) {
            const int j = i | TM;
            float tr = re[i]; re[i] = re[j]; re[j] = tr;
            float ti = im[i]; im[i] = im[j]; im[j] = ti;
        }
}

__device__ inline void rot_rt(int ty, int w, float c, float s, float* re, float* im) {
    switch (ty * 4 + w) {
        case 0:  g_rx<8>(c, s, re, im); break;
        case 1:  g_rx<4>(c, s, re, im); break;
        case 2:  g_rx<2>(c, s, re, im); break;
        case 3:  g_rx<1>(c, s, re, im); break;
        case 4:  g_ry<8>(c, s, re, im); break;
        case 5:  g_ry<4>(c, s, re, im); break;
        case 6:  g_ry<2>(c, s, re, im); break;
        case 7:  g_ry<1>(c, s, re, im); break;
        case 8:  g_rz<8>(c, s, re, im); break;
        case 9:  g_rz<4>(c, s, re, im); break;
        case 10: g_rz<2>(c, s, re, im); break;
        case 11: g_rz<1>(c, s, re, im); break;
        default: break;
    }
}
__device__ inline void cnot_rt(int w0, int w1, float* re, float* im) {
    switch (w0 * 4 + w1) {
        case 1:  g_cnot<8, 4>(re, im); break;
        case 2:  g_cnot<8, 2>(re, im); break;
        case 3:  g_cnot<8, 1>(re, im); break;
        case 4:  g_cnot<4, 8>(re, im); break;
        case 6:  g_cnot<4, 2>(re, im); break;
        case 7:  g_cnot<4, 1>(re, im); break;
        case 8:  g_cnot<2, 8>(re, im); break;
        case 9:  g_cnot<2, 4>(re, im); break;
        case 11: g_cnot<2, 1>(re, im); break;
        case 12: g_cnot<1, 8>(re, im); break;
        case 13: g_cnot<1, 4>(re, im); break;
        case 14: g_cnot<1, 2>(re, im); break;
        default: break;
    }
}

// swizzled channel-last site index for c1 (14x14): row pad + col skew
__device__ inline int c1site(int y, int x) { return y * 15 + x + (x >> 2); }

__device__ inline float dot4(const float4& w, const float4& p) {
    return w.x * p.x + w.y * p.y + w.z * p.z + w.w * p.w;
}

// =====================================================================
// K1: per-image CNN — r17 configuration (BEST: 141.4 us total).
// One image per block (4096 blocks); in-kernel cheap weight permute.
// LEDGER of refuted restructures (do not retry):
//  - (256,4) launch bounds -> 64 VGPR + 2GB scratch spill (r8/r10)
//  - padded-LDS body -> VGPR 256, occ 11% (r12)
//  - r[10] row buffer conv2 -> VGPR 204, occ 11% (r13)
//  - 2 images/block loop -> VGPR 152, occ 11% (r18)
// This body is a fragile allocator equilibrium at VGPR 76 / occ 30%.
// =====================================================================
__global__ __launch_bounds__(256) void k_cnn(
    const float* __restrict__ x,
    const float* __restrict__ c1w, const float* __restrict__ c1b,
    const float* __restrict__ c2w, const float* __restrict__ c2b,
    const float* __restrict__ w1, const float* __restrict__ b1,
    const float* __restrict__ w2, const float* __restrict__ b2,
    const float* __restrict__ w3, const float* __restrict__ b3,
    float* __restrict__ pooled_g, float* __restrict__ mlp_g)
{
    __shared__ __align__(16) float xs[784];
    __shared__ __align__(16) float c1s[216 * 8];
    __shared__ __align__(16) float c2s[784];
    __shared__ __align__(16) float cw1[72], cb1[8], wl2[1152], cb2[16];
    __shared__ float h1s[8];

    const int b = blockIdx.x;
    const int t = threadIdx.x;
    const float4* xb4 = (const float4*)(x + b * 784);
    if (t < 196) ((float4*)xs)[t] = xb4[t];
    if (t < 72) cw1[t] = c1w[t];
    if (t < 8) cb1[t] = c1b[t];
    // cheap permute: t = oc*9+k9 (144 threads), unrolled over 8 ic.
    if (t < 144) {
        const int oc = t / 9, k9 = t - oc * 9;
        const float* src = c2w + oc * 72 + k9;
        float* dst = wl2 + t * 8;
#pragma unroll
        for (int ic = 0; ic < 8; ic++) dst[ic] = src[ic * 9];
    }
    if (t < 16) cb2[t] = c2b[t];
    __syncthreads();

    // avg-pool 6x6 stride 6 -> pooled[16]
    if (t < 16) {
        int r0 = (t >> 2) * 6, c0 = (t & 3) * 6;
        float s = 0.f;
#pragma unroll
        for (int dy = 0; dy < 6; dy++)
#pragma unroll
            for (int dx = 0; dx < 6; dx++)
                s += xs[(r0 + dy) * 28 + (c0 + dx)];
        pooled_g[b * 16 + t] = s * (1.0f / 36.0f);
    }

    // conv1 + relu + 2x2 maxpool: 196 threads x 8 oc, channel-last out
    if (t < 196) {
        const int py = t / 14, px = t % 14;
        const int y0 = 2 * py - 1, x0 = 2 * px - 1;
        float patch[16];
#pragma unroll
        for (int i = 0; i < 4; i++)
#pragma unroll
            for (int j = 0; j < 4; j++) {
                int yy = y0 + i, xx = x0 + j;
                patch[i * 4 + j] = (yy >= 0 && yy < 28 && xx >= 0 && xx < 28)
                                       ? xs[yy * 28 + xx] : 0.f;
            }
        float m8[8];
#pragma unroll
        for (int oc = 0; oc < 8; oc++) {
            float w[9];
#pragma unroll
            for (int i = 0; i < 9; i++) w[i] = cw1[oc * 9 + i];
            float m = 0.f;
#pragma unroll
            for (int dy = 0; dy < 2; dy++)
#pragma unroll
                for (int dx = 0; dx < 2; dx++) {
                    float acc = cb1[oc];
#pragma unroll
                    for (int ky = 0; ky < 3; ky++)
#pragma unroll
                        for (int kx = 0; kx < 3; kx++)
                            acc += w[ky * 3 + kx] * patch[(dy + ky) * 4 + (dx + kx)];
                    m = fmaxf(m, acc);
                }
            m8[oc] = m;
        }
        float4* cv = (float4*)&c1s[c1site(py, px) * 8];
        cv[0] = make_float4(m8[0], m8[1], m8[2], m8[3]);
        cv[1] = make_float4(m8[4], m8[5], m8[6], m8[7]);
    }
    __syncthreads();

    // conv2 + relu + 2x2 maxpool: thread = (oc = t&15, pbase = t>>4)
    {
        const int oc = t & 15;
        const int pbase = t >> 4;
        const float bias = cb2[oc];
        float a[4][2][2];
#pragma unroll
        for (int pi = 0; pi < 4; pi++)
#pragma unroll
            for (int dy = 0; dy < 2; dy++)
#pragma unroll
                for (int dx = 0; dx < 2; dx++) a[pi][dy][dx] = bias;

        const float4* wv = (const float4*)wl2;
        const float4* cv = (const float4*)c1s;
        const float4 z4 = make_float4(0.f, 0.f, 0.f, 0.f);

#pragma unroll
        for (int h = 0; h < 2; h++) {
            float4 W[9];
#pragma unroll
            for (int k = 0; k < 9; k++) W[k] = wv[(oc * 9 + k) * 2 + h];
#pragma unroll
            for (int pi = 0; pi < 4; pi++) {
                const int p = pbase + 16 * pi;
                if (p < 49) {
                    const int py = p / 7, px = p % 7;
                    const int y0 = 2 * py - 1, x0 = 2 * px - 1;
#pragma unroll
                    for (int i = 0; i < 4; i++) {
                        const int y = y0 + i;
                        float4 r[4];
                        if (y >= 0 && y < 14) {
#pragma unroll
                            for (int j = 0; j < 4; j++) {
                                const int xc = x0 + j;
                                r[j] = (xc >= 0 && xc < 14)
                                           ? cv[c1site(y, xc) * 2 + h] : z4;
                            }
                        } else {
#pragma unroll
                            for (int j = 0; j < 4; j++) r[j] = z4;
                        }
#pragma unroll
                        for (int dy = 0; dy < 2; dy++) {
                            if (dy <= i && i <= dy + 2) {  // static under unroll
                                const int ky = i - dy;
                                const float4 wk0 = W[ky * 3 + 0];
                                const float4 wk1 = W[ky * 3 + 1];
                                const float4 wk2 = W[ky * 3 + 2];
                                a[pi][dy][0] += dot4(wk0, r[0]) + dot4(wk1, r[1]) + dot4(wk2, r[2]);
                                a[pi][dy][1] += dot4(wk0, r[1]) + dot4(wk1, r[2]) + dot4(wk2, r[3]);
                            }
                        }
                    }
                }
            }
        }
#pragma unroll
        for (int pi = 0; pi < 4; pi++) {
            const int p = pbase + 16 * pi;
            if (p < 49) {
                float m = fmaxf(fmaxf(a[pi][0][0], a[pi][0][1]),
                                fmaxf(a[pi][1][0], a[pi][1][1]));
                c2s[oc * 49 + p] = fmaxf(m, 0.f);
            }
        }
    }
    __syncthreads();

    // MLP layer1: 8 outputs x 32 lanes each
    {
        int o = t >> 5, lane = t & 31;
        float s = 0.f;
        const float* wrow = w1 + o * 784;
        for (int k = lane; k < 784; k += 32) s += c2s[k] * wrow[k];
#pragma unroll
        for (int d = 16; d > 0; d >>= 1) s += __shfl_down(s, d, 32);
        if (lane == 0) h1s[o] = tanhf(s + b1[o]);
    }
    __syncthreads();
    if (t == 0) {
        float h2[4];
#pragma unroll
        for (int o = 0; o < 4; o++) {
            float s = b2[o];
#pragma unroll
            for (int j = 0; j < 8; j++) s += h1s[j] * w2[o * 8 + j];
            h2[o] = tanhf(s);
        }
        float s = b3[0];
#pragma unroll
        for (int j = 0; j < 4; j++) s += h2[j] * w3[j];
        mlp_g[b] = s;
    }
}

// =====================================================================
// K2: quantum block (unchanged, verified). Block = 1 wave; emits part1.
// =====================================================================
__global__ __launch_bounds__(64) void k_quantum(
    const float* __restrict__ pooled_g, const float* __restrict__ rl,
    const float* __restrict__ prx0, const float* __restrict__ pry0,
    const float* __restrict__ prz0, const float* __restrict__ pcrx0,
    float* __restrict__ qout, float* __restrict__ part1, OpsArg ops)
{
    __shared__ float rc[50], rs[50];
    const int t = threadIdx.x;
    if (t < 50) {
        float a = 0.5f * rl[t];
        rc[t] = cosf(a);
        rs[t] = sinf(a);
    }
    __syncthreads();

    const int b = blockIdx.x * 64 + t;
    float re[16], im[16];
#pragma unroll
    for (int i = 0; i < 16; i++) { re[i] = 0.f; im[i] = 0.f; }
    re[0] = 1.f;

    const float4* pv = (const float4*)(pooled_g + b * 16);
    float pb[16];
    {
        float4 p0 = pv[0], p1 = pv[1], p2 = pv[2], p3 = pv[3];
        pb[0] = p0.x; pb[1] = p0.y; pb[2] = p0.z; pb[3] = p0.w;
        pb[4] = p1.x; pb[5] = p1.y; pb[6] = p1.z; pb[7] = p1.w;
        pb[8] = p2.x; pb[9] = p2.y; pb[10] = p2.z; pb[11] = p2.w;
        pb[12] = p3.x; pb[13] = p3.y; pb[14] = p3.z; pb[15] = p3.w;
    }
    {
        float c, s, a;
        a = 0.5f * pb[0];  c = cosf(a); s = sinf(a); g_ry<8>(c, s, re, im);
        a = 0.5f * pb[1];  c = cosf(a); s = sinf(a); g_ry<4>(c, s, re, im);
        a = 0.5f * pb[2];  c = cosf(a); s = sinf(a); g_ry<2>(c, s, re, im);
        a = 0.5f * pb[3];  c = cosf(a); s = sinf(a); g_ry<1>(c, s, re, im);
        a = 0.5f * pb[4];  c = cosf(a); s = sinf(a); g_rz<8>(c, s, re, im);
        a = 0.5f * pb[5];  c = cosf(a); s = sinf(a); g_rz<4>(c, s, re, im);
        a = 0.5f * pb[6];  c = cosf(a); s = sinf(a); g_rz<2>(c, s, re, im);
        a = 0.5f * pb[7];  c = cosf(a); s = sinf(a); g_rz<1>(c, s, re, im);
        a = 0.5f * pb[8];  c = cosf(a); s = sinf(a); g_rx<8>(c, s, re, im);
        a = 0.5f * pb[9];  c = cosf(a); s = sinf(a); g_rx<4>(c, s, re, im);
        a = 0.5f * pb[10]; c = cosf(a); s = sinf(a); g_rx<2>(c, s, re, im);
        a = 0.5f * pb[11]; c = cosf(a); s = sinf(a); g_rx<1>(c, s, re, im);
        a = 0.5f * pb[12]; c = cosf(a); s = sinf(a); g_ry<8>(c, s, re, im);
        a = 0.5f * pb[13]; c = cosf(a); s = sinf(a); g_ry<4>(c, s, re, im);
        a = 0.5f * pb[14]; c = cosf(a); s = sinf(a); g_ry<2>(c, s, re, im);
        a = 0.5f * pb[15]; c = cosf(a); s = sinf(a); g_ry<1>(c, s, re, im);
    }

#pragma unroll 1
    for (int k = 0; k < 50; k++) {
        int v = ops.v[k];
        int ty = v & 3;
        int w0 = (v >> 2) & 3;
        int w1 = (v >> 4) & 3;
        if (ty == 3) cnot_rt(w0, w1, re, im);
        else         rot_rt(ty, w0, rc[k], rs[k], re, im);
    }

    { float a = 0.5f * prx0[0];  g_rx<8>(cosf(a), sinf(a), re, im); }
    { float a = 0.5f * pry0[0];  g_ry<4>(cosf(a), sinf(a), re, im); }
    { float a = 0.5f * prz0[0];  g_rz<1>(cosf(a), sinf(a), re, im); }
    { // crx (control wire0=mask8, target wire2=mask2)
        float a = 0.5f * pcrx0[0];
        float c = cosf(a), s = sinf(a);
#pragma unroll
        for (int i = 0; i < 16; i++)
            if ((i & 8) && !(i & 2)) {
                const int j = i | 2;
                float r0 = re[i], i0 = im[i], r1 = re[j], i1 = im[j];
                re[i] = c * r0 + s * i1; im[i] = c * i0 - s * r1;
                re[j] = s * i0 + c * r1; im[j] = c * i1 - s * r0;
            }
    }
    { // H wire 3
        const float r2 = 0.70710678118654752f;
#pragma unroll
        for (int i = 0; i < 16; i++)
            if (!(i & 1)) {
                const int j = i | 1;
                float r0 = re[i], i0 = im[i], r1 = re[j], i1 = im[j];
                re[i] = (r0 + r1) * r2; im[i] = (i0 + i1) * r2;
                re[j] = (r0 - r1) * r2; im[j] = (i0 - i1) * r2;
            }
    }
    { // SX wire 2
#pragma unroll
        for (int i = 0; i < 16; i++)
            if (!(i & 2)) {
                const int j = i | 2;
                float r0 = re[i], i0 = im[i], r1 = re[j], i1 = im[j];
                re[i] = 0.5f * (r0 - i0 + r1 + i1);
                im[i] = 0.5f * (r0 + i0 - r1 + i1);
                re[j] = 0.5f * (r0 + i0 + r1 - i1);
                im[j] = 0.5f * (i0 - r0 + r1 + i1);
            }
    }
    g_cnot<1, 8>(re, im);

    float e0 = 0.f, e1 = 0.f, e2 = 0.f, e3 = 0.f;
#pragma unroll
    for (int i = 0; i < 16; i++) {
        float p = re[i] * re[i] + im[i] * im[i];
        e0 += (i & 8) ? -p : p;
        e1 += (i & 4) ? -p : p;
        e2 += (i & 2) ? -p : p;
        e3 += (i & 1) ? -p : p;
    }
    qout[b * 4 + 0] = e0;
    qout[b * 4 + 1] = e1;
    qout[b * 4 + 2] = e2;
    qout[b * 4 + 3] = e3;

    float v0 = e0, v1 = e1, v2 = e2, v3 = e3;
    float q0 = e0 * e0, q1 = e1 * e1, q2 = e2 * e2, q3 = e3 * e3;
#pragma unroll
    for (int d = 32; d > 0; d >>= 1) {
        v0 += __shfl_down(v0, d); v1 += __shfl_down(v1, d);
        v2 += __shfl_down(v2, d); v3 += __shfl_down(v3, d);
        q0 += __shfl_down(q0, d); q1 += __shfl_down(q1, d);
        q2 += __shfl_down(q2, d); q3 += __shfl_down(q3, d);
    }
    if (t == 0) {
        float* p1 = part1 + blockIdx.x * 8;
        p1[0] = v0; p1[1] = v1; p1[2] = v2; p1[3] = v3;
        p1[4] = q0; p1[5] = q1; p1[6] = q2; p1[7] = q3;
    }
}

// =====================================================================
// K3 (fused epilogue): ONE block, 1024 threads (16 waves).
// =====================================================================
__global__ __launch_bounds__(1024) void k_epilogue(
    const float* __restrict__ qout, const float* __restrict__ mlp,
    const float* __restrict__ part1,
    const float* __restrict__ qg, const float* __restrict__ qb,
    const float* __restrict__ fw, const float* __restrict__ fb,
    const float* __restrict__ fg, const float* __restrict__ fbb,
    float* __restrict__ out)
{
    __shared__ float st1[8];
    __shared__ float st2[8];
    __shared__ float wred[16][8];
    __shared__ __align__(16) float fbuf[16384];

    const int t = threadIdx.x;
    const int wave = t >> 6, lane = t & 63;

    if (t < 64) {
        float s[8];
#pragma unroll
        for (int j = 0; j < 8; j++) s[j] = part1[t * 8 + j];
#pragma unroll
        for (int d = 32; d > 0; d >>= 1)
#pragma unroll
            for (int j = 0; j < 8; j++) s[j] += __shfl_down(s[j], d);
        if (t == 0) {
#pragma unroll
            for (int j = 0; j < 4; j++) {
                float mean = s[j] * (1.0f / 4096.0f);
                float var = fmaxf(s[4 + j] * (1.0f / 4096.0f) - mean * mean, 0.0f);
                st1[j] = mean;
                st1[4 + j] = 1.0f / sqrtf(var + 1e-5f);
            }
        }
    }
    __syncthreads();

    float ps[8];
#pragma unroll
    for (int j = 0; j < 8; j++) ps[j] = 0.f;
#pragma unroll
    for (int r = 0; r < 4; r++) {
        const int row = r * 1024 + t;
        const float4 q = ((const float4*)qout)[row];
        float c[5];
        c[0] = mlp[row];
        c[1] = (q.x - st1[0]) * st1[4] * qg[0] + qb[0];
        c[2] = (q.y - st1[1]) * st1[5] * qg[1] + qb[1];
        c[3] = (q.z - st1[2]) * st1[6] * qg[2] + qb[2];
        c[4] = (q.w - st1[3]) * st1[7] * qg[3] + qb[3];
        float fv[4];
#pragma unroll
        for (int o = 0; o < 4; o++) {
            float s = fb[o];
#pragma unroll
            for (int j = 0; j < 5; j++) s += fw[o * 5 + j] * c[j];
            fv[o] = s;
        }
        ((float4*)fbuf)[row] = make_float4(fv[0], fv[1], fv[2], fv[3]);
#pragma unroll
        for (int j = 0; j < 4; j++) {
            ps[j] += fv[j];
            ps[4 + j] += fv[j] * fv[j];
        }
    }
#pragma unroll
    for (int d = 32; d > 0; d >>= 1)
#pragma unroll
        for (int j = 0; j < 8; j++) ps[j] += __shfl_down(ps[j], d);
    if (lane == 0) {
#pragma unroll
        for (int j = 0; j < 8; j++) wred[wave][j] = ps[j];
    }
    __syncthreads();
    if (t < 8) {
        float s = 0.f;
#pragma unroll
        for (int w = 0; w < 16; w++) s += wred[w][t];
        wred[0][t] = s;
    }
    __syncthreads();
    if (t < 4) {
        float mean = wred[0][t] * (1.0f / 4096.0f);
        float var = fmaxf(wred[0][4 + t] * (1.0f / 4096.0f) - mean * mean, 0.0f);
        st2[t] = mean;
        st2[4 + t] = 1.0f / sqrtf(var + 1e-5f);
    }
    __syncthreads();

#pragma unroll
    for (int r = 0; r < 4; r++) {
        const int row = r * 1024 + t;
        const float4 v = ((const float4*)fbuf)[row];
        float4 o;
        o.x = (v.x - st2[0]) * st2[4] * fg[0] + fbb[0];
        o.y = (v.y - st2[1]) * st2[5] * fg[1] + fbb[1];
        o.z = (v.z - st2[2]) * st2[6] * fg[2] + fbb[2];
        o.w = (v.w - st2[3]) * st2[7] * fg[3] + fbb[3];
        ((float4*)out)[row] = o;
    }
}

// K4: diagnostic — only launched if anchors fail
__global__ void k_diag(float* __restrict__ out, float payload)
{
    out[0] = payload;
}

// =====================================================================
extern "C" void kernel_launch(void* const* d_in, const int* in_sizes, int n_in,
                              void* d_out, int out_size, void* d_ws, size_t ws_size,
                              hipStream_t stream) {
    (void)in_sizes; (void)n_in; (void)out_size; (void)ws_size;
    const float* x    = (const float*)d_in[0];
    const float* c1w  = (const float*)d_in[1];
    const float* c1b  = (const float*)d_in[2];
    const float* c2w  = (const float*)d_in[3];
    const float* c2b  = (const float*)d_in[4];
    const float* w1   = (const float*)d_in[5];
    const float* b1   = (const float*)d_in[6];
    const float* w2   = (const float*)d_in[7];
    const float* b2   = (const float*)d_in[8];
    const float* w3   = (const float*)d_in[9];
    const float* b3   = (const float*)d_in[10];
    const float* rl   = (const float*)d_in[11];
    const float* rx0  = (const float*)d_in[12];
    const float* ry0  = (const float*)d_in[13];
    const float* rz0  = (const float*)d_in[14];
    const float* crx0 = (const float*)d_in[15];
    const float* bqg  = (const float*)d_in[16];
    const float* bqb  = (const float*)d_in[17];
    const float* fw   = (const float*)d_in[18];
    const float* fb   = (const float*)d_in[19];
    const float* bfg  = (const float*)d_in[20];
    const float* bfb  = (const float*)d_in[21];

    float* ws = (float*)d_ws;
    float* pooled = ws;            // 4096*16
    float* mlp    = ws + 65536;    // 4096
    float* qout   = ws + 69632;    // 4096*4
    float* part1  = ws + 102400;   // 64*8

    OpsArg ops;
    gen_ops(ops);
    int am = anchors_mask();

    k_cnn<<<4096, 256, 0, stream>>>(x, c1w, c1b, c2w, c2b, w1, b1, w2, b2, w3, b3,
                                    pooled, mlp);
    k_quantum<<<64, 64, 0, stream>>>(pooled, rl, rx0, ry0, rz0, crx0, qout, part1, ops);
    k_epilogue<<<1, 1024, 0, stream>>>(qout, mlp, part1, bqg, bqb, fw, fb,
                                       bfg, bfb, (float*)d_out);
    if (am != 7) {
        k_diag<<<1, 1, 0, stream>>>((float*)d_out, diag_payload(am));
    }
}